// Round 1
// baseline (569.732 us; speedup 1.0000x reference)
//
#include <hip/hip_runtime.h>

// GCN: h = relu(Ahat (xW) + b); g = meanpool(h); out = relu(g W1 + b1) W2 + b2
// Pipeline: Wt convert -> deg count -> dinv -> CSR scan/scatter -> bf16 MFMA GEMM
//           -> per-node gather-aggregate (+bias+relu) -> fused pool+MLP.

typedef short s16x8 __attribute__((ext_vector_type(8)));
typedef unsigned short u16x8 __attribute__((ext_vector_type(8)));
typedef float f32x4 __attribute__((ext_vector_type(4)));

static constexpr int NN  = 50000;   // nodes
static constexpr int NE  = 800000;  // edges
static constexpr int KIN = 512;     // input feature dim
static constexpr int HID = 256;     // hidden dim
static constexpr int NG  = 128;     // graphs

__device__ __forceinline__ unsigned short f2bf(float f) {
  unsigned u = __float_as_uint(f);
  u += 0x7fffu + ((u >> 16) & 1u);   // RNE
  return (unsigned short)(u >> 16);
}

// ---- W [512,256] fp32 -> Wt [256,512] bf16 (transposed so B-fragments are contiguous in k)
__global__ void k_wt(const float* __restrict__ W, unsigned short* __restrict__ wt) {
  int idx = blockIdx.x * 256 + threadIdx.x;     // 131072 total
  int k = idx >> 8, n = idx & 255;
  wt[n * KIN + k] = f2bf(W[idx]);
}

// ---- incoming-degree histogram over dst
__global__ void k_deg(const int* __restrict__ dst, int* __restrict__ cnt) {
  int e = blockIdx.x * 256 + threadIdx.x;
  if (e < NE) atomicAdd(&cnt[dst[e]], 1);
}

__global__ void k_dinv(const int* __restrict__ cnt, float* __restrict__ dinv) {
  int n = blockIdx.x * 256 + threadIdx.x;
  if (n < NN) dinv[n] = rsqrtf((float)cnt[n] + 1.0f);
}

// ---- exclusive scan of cnt[0..NN) into rowptr[0..NN], single block of 1024
__global__ __launch_bounds__(1024) void k_scan(const int* __restrict__ cnt,
                                               int* __restrict__ rowptr) {
  __shared__ int sa[1024], sb[1024];
  const int t = threadIdx.x;
  constexpr int CH = (NN + 1023) / 1024;   // 49
  const int base = t * CH;
  int sum = 0;
  for (int i = 0; i < CH; ++i) { int idx = base + i; if (idx < NN) sum += cnt[idx]; }
  sa[t] = sum;
  __syncthreads();
  int* rd = sa; int* wr = sb;
  for (int off = 1; off < 1024; off <<= 1) {
    int v = rd[t];
    if (t >= off) v += rd[t - off];
    wr[t] = v;
    __syncthreads();
    int* tmp = rd; rd = wr; wr = tmp;
  }
  int run = rd[t] - sum;                    // exclusive offset
  for (int i = 0; i < CH; ++i) {
    const int idx = base + i;
    if (idx <= NN) rowptr[idx] = run;
    if (idx < NN) run += cnt[idx];
  }
}

// ---- scatter edges into CSR-by-dst: col[...] = src
__global__ void k_scatter(const int* __restrict__ dst, const int* __restrict__ src,
                          const int* __restrict__ rowptr, int* __restrict__ fill,
                          int* __restrict__ col) {
  int e = blockIdx.x * 256 + threadIdx.x;
  if (e >= NE) return;
  int d = dst[e];
  int pos = rowptr[d] + atomicAdd(&fill[d], 1);
  col[pos] = src[e];
}

// ---- h = x @ W  (bf16 MFMA, fp32 acc). Tile: BM=64, BN=256 (full N), BK=64.
// 4 waves as 2x2 -> per-wave 32m x 128n. A fused fp32->bf16 reg-staged; B from Wt.
// LDS rows padded to 72 elems (144 B) to break stride-128B bank conflicts.
__global__ __launch_bounds__(256) void k_gemm(const float* __restrict__ x,
                                              const unsigned short* __restrict__ wt,
                                              float* __restrict__ h) {
  __shared__ unsigned short As[64 * 72];
  __shared__ unsigned short Bs[256 * 72];
  const int tid = threadIdx.x;
  const int lane = tid & 63;
  const int wave = tid >> 6;
  const int wm = wave >> 1, wn = wave & 1;
  const int m0 = blockIdx.x * 64;
  const int arow = tid >> 2, aseg = tid & 3;   // A: 4 thr/row, 16 floats each
  const int brow = tid >> 3, bseg = tid & 7;   // B: 8 thr/row, 8 bf16 each, 8 passes
  const int l15 = lane & 15, l4 = lane >> 4;

  f32x4 acc[2][8];
  #pragma unroll
  for (int i = 0; i < 2; ++i)
    #pragma unroll
    for (int j = 0; j < 8; ++j) acc[i][j] = f32x4{0.f, 0.f, 0.f, 0.f};

  for (int kb = 0; kb < KIN; kb += 64) {
    __syncthreads();
    { // stage A (convert fp32 -> bf16)
      const int gm = m0 + arow;
      u16x8 w0 = (u16x8)0, w1 = (u16x8)0;
      if (gm < NN) {
        const f32x4* p = (const f32x4*)(x + (size_t)gm * KIN + kb + aseg * 16);
        f32x4 v0 = p[0], v1 = p[1], v2 = p[2], v3 = p[3];
        float v[16];
        #pragma unroll
        for (int i = 0; i < 4; ++i) { v[i]=v0[i]; v[4+i]=v1[i]; v[8+i]=v2[i]; v[12+i]=v3[i]; }
        #pragma unroll
        for (int i = 0; i < 8; ++i) { w0[i] = f2bf(v[i]); w1[i] = f2bf(v[8 + i]); }
      }
      *(u16x8*)(&As[arow * 72 + aseg * 16])     = w0;
      *(u16x8*)(&As[arow * 72 + aseg * 16 + 8]) = w1;
    }
    // stage B (already bf16, pass through)
    #pragma unroll
    for (int p = 0; p < 8; ++p) {
      const int n = p * 32 + brow;
      u16x8 v = *(const u16x8*)(wt + (size_t)n * KIN + kb + bseg * 8);
      *(u16x8*)(&Bs[n * 72 + bseg * 8]) = v;
    }
    __syncthreads();
    #pragma unroll
    for (int ks = 0; ks < 2; ++ks) {
      s16x8 af[2];
      #pragma unroll
      for (int i = 0; i < 2; ++i) {
        const int row = wm * 32 + i * 16 + l15;
        af[i] = *(const s16x8*)(As + row * 72 + ks * 32 + l4 * 8);
      }
      #pragma unroll
      for (int j = 0; j < 8; ++j) {
        const int nc = wn * 128 + j * 16 + l15;
        s16x8 bfv = *(const s16x8*)(Bs + nc * 72 + ks * 32 + l4 * 8);
        acc[0][j] = __builtin_amdgcn_mfma_f32_16x16x32_bf16(af[0], bfv, acc[0][j], 0, 0, 0);
        acc[1][j] = __builtin_amdgcn_mfma_f32_16x16x32_bf16(af[1], bfv, acc[1][j], 0, 0, 0);
      }
    }
  }
  #pragma unroll
  for (int i = 0; i < 2; ++i)
    #pragma unroll
    for (int r = 0; r < 4; ++r) {
      const int gr = m0 + wm * 32 + i * 16 + l4 * 4 + r;   // C/D: col=lane&15, row=(lane>>4)*4+r
      if (gr < NN) {
        #pragma unroll
        for (int j = 0; j < 8; ++j)
          h[(size_t)gr * HID + wn * 128 + j * 16 + l15] = acc[i][j][r];
      }
    }
}

// ---- aggregate: out[n] = relu( sum_{s in N(n)} h[s]*dinv[s]*dinv[n] + h[n]*dinv[n]^2 + b )
// one wave per node, lane owns 4 contiguous cols (float4)
__global__ __launch_bounds__(256) void k_agg(const float* __restrict__ h,
                                             const int* __restrict__ rowptr,
                                             const int* __restrict__ col,
                                             const float* __restrict__ dinv,
                                             const float* __restrict__ bias,
                                             float* __restrict__ h2) {
  const int n = blockIdx.x * 4 + (threadIdx.x >> 6);
  const int lane = threadIdx.x & 63;
  const f32x4* hp = (const f32x4*)h;
  const float di = dinv[n];
  f32x4 acc = hp[(size_t)n * 64 + lane] * (di * di);
  const int s_ = rowptr[n], e_ = rowptr[n + 1];
  int j = s_;
  for (; j + 1 < e_; j += 2) {   // 2-way unroll for load ILP
    int s0 = col[j], s1 = col[j + 1];
    float w0 = dinv[s0] * di, w1 = dinv[s1] * di;
    f32x4 v0 = hp[(size_t)s0 * 64 + lane];
    f32x4 v1 = hp[(size_t)s1 * 64 + lane];
    acc += v0 * w0 + v1 * w1;
  }
  if (j < e_) {
    int s0 = col[j];
    acc += hp[(size_t)s0 * 64 + lane] * (dinv[s0] * di);
  }
  acc += ((const f32x4*)bias)[lane];
  f32x4 r;
  r[0] = fmaxf(acc[0], 0.f); r[1] = fmaxf(acc[1], 0.f);
  r[2] = fmaxf(acc[2], 0.f); r[3] = fmaxf(acc[3], 0.f);
  ((f32x4*)h2)[(size_t)n * 64 + lane] = r;
}

// ---- fused mean-pool (batch sorted -> binary search) + 2-layer MLP
__global__ __launch_bounds__(1024) void k_pool(const float* __restrict__ h2,
                                               const int* __restrict__ batch,
                                               const float* __restrict__ W1,
                                               const float* __restrict__ b1,
                                               const float* __restrict__ W2,
                                               const float* __restrict__ b2,
                                               float* __restrict__ out) {
  __shared__ float gp[4][256];
  __shared__ float gs[256];
  __shared__ float a1[16];
  const int gi = blockIdx.x;
  const int tid = threadIdx.x;
  const int colc = tid & 255, q = tid >> 8;
  int lo = 0, hi = NN;
  while (lo < hi) { int mid = (lo + hi) >> 1; if (batch[mid] < gi) lo = mid + 1; else hi = mid; }
  const int s_ = lo;
  hi = NN;
  while (lo < hi) { int mid = (lo + hi) >> 1; if (batch[mid] < gi + 1) lo = mid + 1; else hi = mid; }
  const int e_ = lo;
  float sum = 0.f;
  for (int n = s_ + q; n < e_; n += 4) sum += h2[(size_t)n * HID + colc];
  gp[q][colc] = sum;
  __syncthreads();
  if (q == 0) {
    float tot = gp[0][colc] + gp[1][colc] + gp[2][colc] + gp[3][colc];
    float c = (float)(e_ - s_);
    gs[colc] = tot / fmaxf(c, 1.0f);
  }
  __syncthreads();
  if (tid < 16) {
    float acc = b1[tid];
    #pragma unroll 4
    for (int k = 0; k < 256; ++k) acc += gs[k] * W1[k * 16 + tid];
    a1[tid] = fmaxf(acc, 0.0f);
  }
  __syncthreads();
  if (tid < 10) {
    float acc = b2[tid];
    #pragma unroll
    for (int k = 0; k < 16; ++k) acc += a1[k] * W2[k * 10 + tid];
    out[gi * 10 + tid] = acc;
  }
}

extern "C" void kernel_launch(void* const* d_in, const int* in_sizes, int n_in,
                              void* d_out, int out_size, void* d_ws, size_t ws_size,
                              hipStream_t stream) {
  const float* x     = (const float*)d_in[0];
  const int*   ei    = (const int*)d_in[1];      // [2,E]: src then dst
  const int*   batch = (const int*)d_in[2];
  const float* W     = (const float*)d_in[3];
  const float* b     = (const float*)d_in[4];
  const float* W1    = (const float*)d_in[5];
  const float* b1    = (const float*)d_in[6];
  const float* W2    = (const float*)d_in[7];
  const float* b2    = (const float*)d_in[8];
  float* out = (float*)d_out;
  char* ws = (char*)d_ws;

  size_t o = 0;
  auto al = [&](size_t bytes) { size_t r = o; o = (o + bytes + 255) & ~(size_t)255; return r; };
  unsigned short* wt   = (unsigned short*)(ws + al((size_t)KIN * HID * 2));
  float* dinv          = (float*)(ws + al((size_t)NN * 4));
  int*   cnt           = (int*)(ws + al((size_t)NN * 4));
  int*   fill          = (int*)(ws + al((size_t)NN * 4));
  int*   rowptr        = (int*)(ws + al((size_t)(NN + 1) * 4));
  int*   col           = (int*)(ws + al((size_t)NE * 4));
  float* h             = (float*)(ws + al((size_t)NN * HID * 4));
  float* h2            = (float*)(ws + al((size_t)NN * HID * 4));

  const int* src = ei;
  const int* dst = ei + NE;

  // zero cnt + fill (adjacent region)
  hipMemsetAsync(cnt, 0, (size_t)((char*)fill - (char*)cnt) + (size_t)NN * 4, stream);

  k_wt     <<<(KIN * HID) / 256, 256, 0, stream>>>(W, wt);
  k_deg    <<<(NE + 255) / 256, 256, 0, stream>>>(dst, cnt);
  k_dinv   <<<(NN + 255) / 256, 256, 0, stream>>>(cnt, dinv);
  k_scan   <<<1, 1024, 0, stream>>>(cnt, rowptr);
  k_scatter<<<(NE + 255) / 256, 256, 0, stream>>>(dst, src, rowptr, fill, col);
  k_gemm   <<<(NN + 63) / 64, 256, 0, stream>>>(x, wt, h);
  k_agg    <<<NN / 4, 256, 0, stream>>>(h, rowptr, col, dinv, b, h2);
  k_pool   <<<NG, 1024, 0, stream>>>(h2, batch, W1, b1, W2, b2, out);
}

// Round 2
// 392.637 us; speedup vs baseline: 1.4510x; 1.4510x over previous
//
#include <hip/hip_runtime.h>

// GCN: h = relu(Ahat (xW) + b); g = meanpool(h); out = relu(g W1 + b1) W2 + b2
// Pipeline: Wt convert -> deg -> dinv -> hierarchical CSR scan -> scatter
//           -> bf16 MFMA GEMM (epilogue: *dinv, ->bf16 "hs") -> gather-agg (bf16)
//           -> fused pool+MLP.

typedef short s16x8 __attribute__((ext_vector_type(8)));
typedef unsigned short u16x8 __attribute__((ext_vector_type(8)));
typedef float f32x4 __attribute__((ext_vector_type(4)));

static constexpr int NN  = 50000;   // nodes
static constexpr int NE  = 800000;  // edges
static constexpr int KIN = 512;     // input feature dim
static constexpr int HID = 256;     // hidden dim
static constexpr int NG  = 128;     // graphs
static constexpr int NB  = (NN + 255) / 256;   // scan blocks = 196

__device__ __forceinline__ unsigned short f2bf(float f) {
  unsigned u = __float_as_uint(f);
  u += 0x7fffu + ((u >> 16) & 1u);   // RNE
  return (unsigned short)(u >> 16);
}

__device__ __forceinline__ f32x4 bf4_to_f32(uint2 u) {
  f32x4 r;
  r[0] = __uint_as_float(u.x << 16);
  r[1] = __uint_as_float(u.x & 0xffff0000u);
  r[2] = __uint_as_float(u.y << 16);
  r[3] = __uint_as_float(u.y & 0xffff0000u);
  return r;
}

__device__ __forceinline__ uint2 f32_to_bf4(f32x4 v) {
  uint2 r;
  r.x = (unsigned)f2bf(v[0]) | ((unsigned)f2bf(v[1]) << 16);
  r.y = (unsigned)f2bf(v[2]) | ((unsigned)f2bf(v[3]) << 16);
  return r;
}

// ---- W [512,256] fp32 -> Wt [256,512] bf16 (transposed: B-fragments contiguous in k)
__global__ void k_wt(const float* __restrict__ W, unsigned short* __restrict__ wt) {
  int idx = blockIdx.x * 256 + threadIdx.x;     // 131072 total
  int k = idx >> 8, n = idx & 255;
  wt[n * KIN + k] = f2bf(W[idx]);
}

// ---- incoming-degree histogram over dst
__global__ void k_deg(const int* __restrict__ dst, int* __restrict__ cnt) {
  int e = blockIdx.x * 256 + threadIdx.x;
  if (e < NE) atomicAdd(&cnt[dst[e]], 1);
}

__global__ void k_dinv(const int* __restrict__ cnt, float* __restrict__ dinv) {
  int n = blockIdx.x * 256 + threadIdx.x;
  if (n < NN) dinv[n] = rsqrtf((float)cnt[n] + 1.0f);
}

// ---- hierarchical exclusive scan of cnt -> rowptr
__global__ __launch_bounds__(256) void k_scan1(const int* __restrict__ cnt,
                                               int* __restrict__ bsum) {
  __shared__ int s[256];
  const int t = threadIdx.x;
  const int i = blockIdx.x * 256 + t;
  s[t] = (i < NN) ? cnt[i] : 0;
  __syncthreads();
  for (int off = 128; off > 0; off >>= 1) {
    if (t < off) s[t] += s[t + off];
    __syncthreads();
  }
  if (t == 0) bsum[blockIdx.x] = s[0];
}

__global__ __launch_bounds__(256) void k_scan2(const int* __restrict__ bsum,
                                               int* __restrict__ boff,
                                               int* __restrict__ rowptr) {
  __shared__ int sa[256], sb[256];
  const int t = threadIdx.x;
  int v = (t < NB) ? bsum[t] : 0;
  sa[t] = v;
  __syncthreads();
  int* rd = sa; int* wr = sb;
  for (int off = 1; off < 256; off <<= 1) {
    int u = rd[t];
    if (t >= off) u += rd[t - off];
    wr[t] = u;
    __syncthreads();
    int* tmp = rd; rd = wr; wr = tmp;
  }
  if (t < NB) boff[t] = rd[t] - v;     // exclusive
  if (t == 255) rowptr[NN] = rd[255];  // total = NE
}

__global__ __launch_bounds__(256) void k_scan3(const int* __restrict__ cnt,
                                               const int* __restrict__ boff,
                                               int* __restrict__ rowptr) {
  __shared__ int sa[256], sb[256];
  const int t = threadIdx.x;
  const int i = blockIdx.x * 256 + t;
  int v = (i < NN) ? cnt[i] : 0;
  sa[t] = v;
  __syncthreads();
  int* rd = sa; int* wr = sb;
  for (int off = 1; off < 256; off <<= 1) {
    int u = rd[t];
    if (t >= off) u += rd[t - off];
    wr[t] = u;
    __syncthreads();
    int* tmp = rd; rd = wr; wr = tmp;
  }
  if (i < NN) rowptr[i] = rd[t] - v + boff[blockIdx.x];
}

// ---- scatter edges into CSR-by-dst: col[...] = src
__global__ void k_scatter(const int* __restrict__ dst, const int* __restrict__ src,
                          const int* __restrict__ rowptr, int* __restrict__ fill,
                          int* __restrict__ col) {
  int e = blockIdx.x * 256 + threadIdx.x;
  if (e >= NE) return;
  int d = dst[e];
  int pos = rowptr[d] + atomicAdd(&fill[d], 1);
  col[pos] = src[e];
}

// ---- hs = (x @ W) * dinv[row], stored bf16.  BM=128, BN=256(full), BK=64, 8 waves.
__global__ __launch_bounds__(512) void k_gemm(const float* __restrict__ x,
                                              const unsigned short* __restrict__ wt,
                                              const float* __restrict__ dinv,
                                              unsigned short* __restrict__ hs) {
  __shared__ unsigned short As[128 * 72];
  __shared__ unsigned short Bs[256 * 72];
  const int tid = threadIdx.x;
  const int lane = tid & 63;
  const int wave = tid >> 6;            // 8 waves: 2(m) x 4(n)
  const int wm = wave >> 2, wn = wave & 3;
  const int m0 = blockIdx.x * 128;
  const int arow = tid >> 2, aseg = tid & 3;   // A stage: 4 thr/row, 16 floats
  const int l15 = lane & 15, l4 = lane >> 4;

  f32x4 acc[4][4];
  #pragma unroll
  for (int i = 0; i < 4; ++i)
    #pragma unroll
    for (int j = 0; j < 4; ++j) acc[i][j] = f32x4{0.f, 0.f, 0.f, 0.f};

  for (int kb = 0; kb < KIN; kb += 64) {
    __syncthreads();
    { // stage A (fp32 -> bf16)
      const int gm = m0 + arow;
      u16x8 w0 = (u16x8)0, w1 = (u16x8)0;
      if (gm < NN) {
        const f32x4* p = (const f32x4*)(x + (size_t)gm * KIN + kb + aseg * 16);
        f32x4 v0 = p[0], v1 = p[1], v2 = p[2], v3 = p[3];
        float v[16];
        #pragma unroll
        for (int i = 0; i < 4; ++i) { v[i]=v0[i]; v[4+i]=v1[i]; v[8+i]=v2[i]; v[12+i]=v3[i]; }
        #pragma unroll
        for (int i = 0; i < 8; ++i) { w0[i] = f2bf(v[i]); w1[i] = f2bf(v[8 + i]); }
      }
      *(u16x8*)(&As[arow * 72 + aseg * 16])     = w0;
      *(u16x8*)(&As[arow * 72 + aseg * 16 + 8]) = w1;
    }
    // stage B (bf16 pass-through): 2 passes x 128 rows, 4 thr/row, 16 bf16 each
    #pragma unroll
    for (int p = 0; p < 2; ++p) {
      const int n = p * 128 + (tid >> 2);
      const int seg = tid & 3;
      u16x8 v0 = *(const u16x8*)(wt + (size_t)n * KIN + kb + seg * 16);
      u16x8 v1 = *(const u16x8*)(wt + (size_t)n * KIN + kb + seg * 16 + 8);
      *(u16x8*)(&Bs[n * 72 + seg * 16])     = v0;
      *(u16x8*)(&Bs[n * 72 + seg * 16 + 8]) = v1;
    }
    __syncthreads();
    #pragma unroll
    for (int ks = 0; ks < 2; ++ks) {
      s16x8 af[4], bfv[4];
      #pragma unroll
      for (int i = 0; i < 4; ++i) {
        const int row = wm * 64 + i * 16 + l15;
        af[i] = *(const s16x8*)(As + row * 72 + ks * 32 + l4 * 8);
      }
      #pragma unroll
      for (int j = 0; j < 4; ++j) {
        const int nc = wn * 64 + j * 16 + l15;
        bfv[j] = *(const s16x8*)(Bs + nc * 72 + ks * 32 + l4 * 8);
      }
      #pragma unroll
      for (int i = 0; i < 4; ++i)
        #pragma unroll
        for (int j = 0; j < 4; ++j)
          acc[i][j] = __builtin_amdgcn_mfma_f32_16x16x32_bf16(af[i], bfv[j], acc[i][j], 0, 0, 0);
    }
  }
  // epilogue: hs[row, col] = bf16(acc * dinv[row])
  #pragma unroll
  for (int i = 0; i < 4; ++i)
    #pragma unroll
    for (int r = 0; r < 4; ++r) {
      const int gr = m0 + wm * 64 + i * 16 + l4 * 4 + r;   // C/D: col=lane&15, row=(lane>>4)*4+r
      if (gr < NN) {
        const float sc = dinv[gr];
        #pragma unroll
        for (int j = 0; j < 4; ++j)
          hs[(size_t)gr * HID + wn * 64 + j * 16 + l15] = f2bf(acc[i][j][r] * sc);
      }
    }
}

// ---- aggregate: h2[n] = relu( dinv[n] * (hs[n] + sum_{s in N(n)} hs[s]) + b ), bf16 out
// one wave per node, lane owns 4 cols (8B bf16x4)
__global__ __launch_bounds__(256) void k_agg(const unsigned short* __restrict__ hs,
                                             const int* __restrict__ rowptr,
                                             const int* __restrict__ col,
                                             const float* __restrict__ dinv,
                                             const float* __restrict__ bias,
                                             unsigned short* __restrict__ h2) {
  const int n = blockIdx.x * 4 + (threadIdx.x >> 6);
  const int lane = threadIdx.x & 63;
  const uint2* hp = (const uint2*)hs;          // row = 64 uint2
  f32x4 acc = bf4_to_f32(hp[(size_t)n * 64 + lane]);   // self term (pre-scaled by dinv[n])
  const int s_ = rowptr[n], e_ = rowptr[n + 1];
  int j = s_;
  for (; j + 3 < e_; j += 4) {
    int s0 = col[j], s1 = col[j + 1], s2 = col[j + 2], s3 = col[j + 3];
    uint2 v0 = hp[(size_t)s0 * 64 + lane];
    uint2 v1 = hp[(size_t)s1 * 64 + lane];
    uint2 v2 = hp[(size_t)s2 * 64 + lane];
    uint2 v3 = hp[(size_t)s3 * 64 + lane];
    acc += bf4_to_f32(v0) + bf4_to_f32(v1) + bf4_to_f32(v2) + bf4_to_f32(v3);
  }
  for (; j < e_; ++j) {
    int s0 = col[j];
    acc += bf4_to_f32(hp[(size_t)s0 * 64 + lane]);
  }
  const float dn = dinv[n];
  f32x4 bv = ((const f32x4*)bias)[lane];
  f32x4 r;
  #pragma unroll
  for (int c = 0; c < 4; ++c) r[c] = fmaxf(acc[c] * dn + bv[c], 0.f);
  ((uint2*)h2)[(size_t)n * 64 + lane] = f32_to_bf4(r);
}

// ---- fused mean-pool (batch sorted -> binary search) + 2-layer MLP
__global__ __launch_bounds__(1024) void k_pool(const unsigned short* __restrict__ h2,
                                               const int* __restrict__ batch,
                                               const float* __restrict__ W1,
                                               const float* __restrict__ b1,
                                               const float* __restrict__ W2,
                                               const float* __restrict__ b2,
                                               float* __restrict__ out) {
  __shared__ float gp[4][256];
  __shared__ float gs[256];
  __shared__ float a1[16];
  const int gi = blockIdx.x;
  const int tid = threadIdx.x;
  const int colc = tid & 255, q = tid >> 8;
  int lo = 0, hi = NN;
  while (lo < hi) { int mid = (lo + hi) >> 1; if (batch[mid] < gi) lo = mid + 1; else hi = mid; }
  const int s_ = lo;
  hi = NN;
  while (lo < hi) { int mid = (lo + hi) >> 1; if (batch[mid] < gi + 1) lo = mid + 1; else hi = mid; }
  const int e_ = lo;
  float sum = 0.f;
  for (int n = s_ + q; n < e_; n += 4)
    sum += __uint_as_float(((unsigned)h2[(size_t)n * HID + colc]) << 16);
  gp[q][colc] = sum;
  __syncthreads();
  if (q == 0) {
    float tot = gp[0][colc] + gp[1][colc] + gp[2][colc] + gp[3][colc];
    float c = (float)(e_ - s_);
    gs[colc] = tot / fmaxf(c, 1.0f);
  }
  __syncthreads();
  if (tid < 16) {
    float acc = b1[tid];
    #pragma unroll 4
    for (int k = 0; k < 256; ++k) acc += gs[k] * W1[k * 16 + tid];
    a1[tid] = fmaxf(acc, 0.0f);
  }
  __syncthreads();
  if (tid < 10) {
    float acc = b2[tid];
    #pragma unroll
    for (int k = 0; k < 16; ++k) acc += a1[k] * W2[k * 10 + tid];
    out[gi * 10 + tid] = acc;
  }
}

extern "C" void kernel_launch(void* const* d_in, const int* in_sizes, int n_in,
                              void* d_out, int out_size, void* d_ws, size_t ws_size,
                              hipStream_t stream) {
  const float* x     = (const float*)d_in[0];
  const int*   ei    = (const int*)d_in[1];      // [2,E]: src then dst
  const int*   batch = (const int*)d_in[2];
  const float* W     = (const float*)d_in[3];
  const float* b     = (const float*)d_in[4];
  const float* W1    = (const float*)d_in[5];
  const float* b1    = (const float*)d_in[6];
  const float* W2    = (const float*)d_in[7];
  const float* b2    = (const float*)d_in[8];
  float* out = (float*)d_out;
  char* ws = (char*)d_ws;

  size_t o = 0;
  auto al = [&](size_t bytes) { size_t r = o; o = (o + bytes + 255) & ~(size_t)255; return r; };
  unsigned short* wt = (unsigned short*)(ws + al((size_t)KIN * HID * 2));
  float* dinv        = (float*)(ws + al((size_t)NN * 4));
  int*   cnt         = (int*)(ws + al((size_t)NN * 4));
  int*   fill        = (int*)(ws + al((size_t)NN * 4));
  int*   rowptr      = (int*)(ws + al((size_t)(NN + 1) * 4));
  int*   col         = (int*)(ws + al((size_t)NE * 4));
  int*   bsum        = (int*)(ws + al((size_t)256 * 4));
  int*   boff        = (int*)(ws + al((size_t)256 * 4));
  unsigned short* hs = (unsigned short*)(ws + al((size_t)NN * HID * 2));
  unsigned short* h2 = (unsigned short*)(ws + al((size_t)NN * HID * 2));

  const int* src = ei;
  const int* dst = ei + NE;

  // zero cnt + fill (adjacent region)
  hipMemsetAsync(cnt, 0, (size_t)((char*)fill - (char*)cnt) + (size_t)NN * 4, stream);

  k_wt     <<<(KIN * HID) / 256, 256, 0, stream>>>(W, wt);
  k_deg    <<<(NE + 255) / 256, 256, 0, stream>>>(dst, cnt);
  k_dinv   <<<(NN + 255) / 256, 256, 0, stream>>>(cnt, dinv);
  k_scan1  <<<NB, 256, 0, stream>>>(cnt, bsum);
  k_scan2  <<<1, 256, 0, stream>>>(bsum, boff, rowptr);
  k_scan3  <<<NB, 256, 0, stream>>>(cnt, boff, rowptr);
  k_scatter<<<(NE + 255) / 256, 256, 0, stream>>>(dst, src, rowptr, fill, col);
  k_gemm   <<<(NN + 127) / 128, 512, 0, stream>>>(x, wt, dinv, hs);
  k_agg    <<<NN / 4, 256, 0, stream>>>(hs, rowptr, col, dinv, b, h2);
  k_pool   <<<NG, 1024, 0, stream>>>(h2, batch, W1, b1, W2, b2, out);
}

// Round 3
// 368.312 us; speedup vs baseline: 1.5469x; 1.0660x over previous
//
#include <hip/hip_runtime.h>

// GCN: h = relu(Ahat (xW) + b); g = meanpool(h); out = relu(g W1 + b1) W2 + b2
// R3: fused fp32-A MFMA GEMM (global_load_lds + source-XOR-swizzle + cvt_pk),
//     half-wave-per-edge gather, vectorized pool.

typedef short s16x8 __attribute__((ext_vector_type(8)));
typedef unsigned short u16x8 __attribute__((ext_vector_type(8)));
typedef float f32x4 __attribute__((ext_vector_type(4)));

static constexpr int NN  = 50000;   // nodes
static constexpr int NE  = 800000;  // edges
static constexpr int KIN = 512;     // input feature dim
static constexpr int HID = 256;     // hidden dim
static constexpr int NG  = 128;     // graphs
static constexpr int NB  = (NN + 255) / 256;   // scan blocks = 196

__device__ __forceinline__ unsigned short f2bf(float f) {
  unsigned u = __float_as_uint(f);
  u += 0x7fffu + ((u >> 16) & 1u);   // RNE
  return (unsigned short)(u >> 16);
}

__device__ __forceinline__ unsigned cvtpk(float lo, float hi) {
  unsigned r;
  asm("v_cvt_pk_bf16_f32 %0, %1, %2" : "=v"(r) : "v"(lo), "v"(hi));
  return r;  // low16 = bf16(lo), high16 = bf16(hi)
}

__device__ __forceinline__ f32x4 bf4_to_f32(uint2 u) {
  f32x4 r;
  r[0] = __uint_as_float(u.x << 16);
  r[1] = __uint_as_float(u.x & 0xffff0000u);
  r[2] = __uint_as_float(u.y << 16);
  r[3] = __uint_as_float(u.y & 0xffff0000u);
  return r;
}

__device__ __forceinline__ void glds16(const void* g, void* l) {
  __builtin_amdgcn_global_load_lds(
      (const __attribute__((address_space(1))) void*)g,
      (__attribute__((address_space(3))) void*)l, 16, 0, 0);
}

// ---- W [512,256] fp32 -> Wt [256,512] bf16 (transposed: B-fragments contiguous in k)
__global__ void k_wt(const float* __restrict__ W, unsigned short* __restrict__ wt) {
  int idx = blockIdx.x * 256 + threadIdx.x;     // 131072 total
  int k = idx >> 8, n = idx & 255;
  wt[n * KIN + k] = f2bf(W[idx]);
}

// ---- incoming-degree histogram over dst
__global__ void k_deg(const int* __restrict__ dst, int* __restrict__ cnt) {
  int e = blockIdx.x * 256 + threadIdx.x;
  if (e < NE) atomicAdd(&cnt[dst[e]], 1);
}

__global__ void k_dinv(const int* __restrict__ cnt, float* __restrict__ dinv) {
  int n = blockIdx.x * 256 + threadIdx.x;
  if (n < NN) dinv[n] = rsqrtf((float)cnt[n] + 1.0f);
}

// ---- hierarchical exclusive scan of cnt -> rowptr
__global__ __launch_bounds__(256) void k_scan1(const int* __restrict__ cnt,
                                               int* __restrict__ bsum) {
  __shared__ int s[256];
  const int t = threadIdx.x;
  const int i = blockIdx.x * 256 + t;
  s[t] = (i < NN) ? cnt[i] : 0;
  __syncthreads();
  for (int off = 128; off > 0; off >>= 1) {
    if (t < off) s[t] += s[t + off];
    __syncthreads();
  }
  if (t == 0) bsum[blockIdx.x] = s[0];
}

__global__ __launch_bounds__(256) void k_scan2(const int* __restrict__ bsum,
                                               int* __restrict__ boff,
                                               int* __restrict__ rowptr) {
  __shared__ int sa[256], sb[256];
  const int t = threadIdx.x;
  int v = (t < NB) ? bsum[t] : 0;
  sa[t] = v;
  __syncthreads();
  int* rd = sa; int* wr = sb;
  for (int off = 1; off < 256; off <<= 1) {
    int u = rd[t];
    if (t >= off) u += rd[t - off];
    wr[t] = u;
    __syncthreads();
    int* tmp = rd; rd = wr; wr = tmp;
  }
  if (t < NB) boff[t] = rd[t] - v;     // exclusive
  if (t == 255) rowptr[NN] = rd[255];  // total = NE
}

__global__ __launch_bounds__(256) void k_scan3(const int* __restrict__ cnt,
                                               const int* __restrict__ boff,
                                               int* __restrict__ rowptr) {
  __shared__ int sa[256], sb[256];
  const int t = threadIdx.x;
  const int i = blockIdx.x * 256 + t;
  int v = (i < NN) ? cnt[i] : 0;
  sa[t] = v;
  __syncthreads();
  int* rd = sa; int* wr = sb;
  for (int off = 1; off < 256; off <<= 1) {
    int u = rd[t];
    if (t >= off) u += rd[t - off];
    wr[t] = u;
    __syncthreads();
    int* tmp = rd; rd = wr; wr = tmp;
  }
  if (i < NN) rowptr[i] = rd[t] - v + boff[blockIdx.x];
}

// ---- scatter edges into CSR-by-dst: col[...] = src
__global__ void k_scatter(const int* __restrict__ dst, const int* __restrict__ src,
                          const int* __restrict__ rowptr, int* __restrict__ fill,
                          int* __restrict__ col) {
  int e = blockIdx.x * 256 + threadIdx.x;
  if (e >= NE) return;
  int d = dst[e];
  int pos = rowptr[d] + atomicAdd(&fill[d], 1);
  col[pos] = src[e];
}

// ---- hs = (x @ W) * dinv[row] -> bf16.  BM=128, BN=128, BK=64, 4 waves (2x2).
// A staged fp32 via global_load_lds (16B), B bf16 via global_load_lds.
// Source-XOR swizzle (chunk ^= row&7) keeps LDS linear but conflict-free reads.
// fp32->bf16 conversion fused into fragment read via v_cvt_pk_bf16_f32.
__global__ __launch_bounds__(256) void k_gemm(const float* __restrict__ x,
                                              const unsigned short* __restrict__ wt,
                                              const float* __restrict__ dinv,
                                              unsigned short* __restrict__ hs) {
  __shared__ float          As[128 * 64];   // 32 KB, [row][64 f32], chunks swizzled
  __shared__ unsigned short Bs[128 * 64];   // 16 KB, [row][64 bf16], chunks swizzled
  const int tid  = threadIdx.x;
  const int lane = tid & 63;
  const int w    = tid >> 6;
  const int wm = w >> 1, wn = w & 1;
  const int bm = (int)blockIdx.x >> 1, bn = (int)blockIdx.x & 1;
  const int m0 = bm * 128, n0 = bn * 128;
  const int l15 = lane & 15, l4 = lane >> 4;

  // A staging: issue covers 16 rows (4 KB); lane -> row w*4 + (lane>>4), chunk lane&15
  const int ra_l = w * 4 + (lane >> 4);
  const int ca_sw = (lane & 15) ^ (ra_l & 7);      // swizzled source chunk (16B units of 4 f32)
  // B staging: issue covers 32 rows (4 KB); lane -> row w*8 + (lane>>3), chunk lane&7
  const int rb_l = w * 8 + (lane >> 3);
  const int cb_sw = (lane & 7) ^ (rb_l & 7);       // 16B units of 8 bf16

  f32x4 acc[4][4];
  #pragma unroll
  for (int i = 0; i < 4; ++i)
    #pragma unroll
    for (int j = 0; j < 4; ++j) acc[i][j] = f32x4{0.f, 0.f, 0.f, 0.f};

  const int msw = l15 & 7;                          // read-side swizzle key

  for (int kb = 0; kb < KIN; kb += 64) {
    __syncthreads();
    #pragma unroll
    for (int i = 0; i < 8; ++i) {                   // A: 8 issues x 16 rows
      int r = i * 16 + ra_l;
      int gr = m0 + r; if (gr > NN - 1) gr = NN - 1;
      glds16(x + (size_t)gr * KIN + kb + ca_sw * 4, &As[(i * 16 + w * 4) * 64]);
    }
    #pragma unroll
    for (int i = 0; i < 4; ++i) {                   // B: 4 issues x 32 rows
      int r = i * 32 + rb_l;
      glds16(wt + (size_t)(n0 + r) * KIN + kb + cb_sw * 8, &Bs[(i * 32 + w * 8) * 64]);
    }
    __syncthreads();
    #pragma unroll
    for (int ks = 0; ks < 2; ++ks) {
      union { unsigned u[4]; s16x8 v; } af[4];
      s16x8 bfr[4];
      #pragma unroll
      for (int i = 0; i < 4; ++i) {
        const int r = wm * 64 + i * 16 + l15;
        const float* arow = As + r * 64;
        const int c0 = ks * 8 + l4 * 2;             // even 16B chunk
        const int p0 = c0 ^ msw;
        f32x4 u0 = *(const f32x4*)(arow + p0 * 4);
        f32x4 u1 = *(const f32x4*)(arow + (p0 ^ 1) * 4);
        af[i].u[0] = cvtpk(u0[0], u0[1]);
        af[i].u[1] = cvtpk(u0[2], u0[3]);
        af[i].u[2] = cvtpk(u1[0], u1[1]);
        af[i].u[3] = cvtpk(u1[2], u1[3]);
      }
      #pragma unroll
      for (int j = 0; j < 4; ++j) {
        const int r = wn * 64 + j * 16 + l15;
        const int c = ks * 4 + l4;
        bfr[j] = *(const s16x8*)(Bs + r * 64 + (c ^ msw) * 8);
      }
      #pragma unroll
      for (int i = 0; i < 4; ++i)
        #pragma unroll
        for (int j = 0; j < 4; ++j)
          acc[i][j] = __builtin_amdgcn_mfma_f32_16x16x32_bf16(af[i].v, bfr[j], acc[i][j], 0, 0, 0);
    }
  }
  // epilogue: hs[row, col] = bf16(acc * dinv[row]); C/D: col=lane&15, row=(lane>>4)*4+r
  #pragma unroll
  for (int i = 0; i < 4; ++i)
    #pragma unroll
    for (int r = 0; r < 4; ++r) {
      const int gr = m0 + wm * 64 + i * 16 + l4 * 4 + r;
      if (gr < NN) {
        const float sc = dinv[gr];
        #pragma unroll
        for (int j = 0; j < 4; ++j)
          hs[(size_t)gr * HID + n0 + wn * 64 + j * 16 + l15] = f2bf(acc[i][j][r] * sc);
      }
    }
}

// ---- aggregate: h2[n] = relu( dinv[n]*(hs[n] + sum_{s in N(n)} hs[s]) + b ), bf16 out
// one wave per node; two half-waves take alternate edges; lane&31 owns 16B (8 cols)
__global__ __launch_bounds__(256) void k_agg(const unsigned short* __restrict__ hs,
                                             const int* __restrict__ rowptr,
                                             const int* __restrict__ col,
                                             const float* __restrict__ dinv,
                                             const float* __restrict__ bias,
                                             unsigned short* __restrict__ h2) {
  const int n = blockIdx.x * 4 + (threadIdx.x >> 6);
  const int lane = threadIdx.x & 63;
  const int half = lane >> 5, q = lane & 31;
  const uint4* hp = (const uint4*)hs;               // 32 uint4 per row
  f32x4 a0 = {0.f,0.f,0.f,0.f}, a1 = {0.f,0.f,0.f,0.f};
  if (half == 0) {                                  // self term once
    uint4 v = hp[(size_t)n * 32 + q];
    a0 += bf4_to_f32(uint2{v.x, v.y}); a1 += bf4_to_f32(uint2{v.z, v.w});
  }
  const int s_ = rowptr[n], e_ = rowptr[n + 1];
  int j = s_ + half;
  for (; j + 2 < e_; j += 4) {                      // 2 edges in flight per half-wave
    int s0 = col[j], s1 = col[j + 2];
    uint4 v0 = hp[(size_t)s0 * 32 + q];
    uint4 v1 = hp[(size_t)s1 * 32 + q];
    a0 += bf4_to_f32(uint2{v0.x, v0.y}); a1 += bf4_to_f32(uint2{v0.z, v0.w});
    a0 += bf4_to_f32(uint2{v1.x, v1.y}); a1 += bf4_to_f32(uint2{v1.z, v1.w});
  }
  if (j < e_) {
    uint4 v = hp[(size_t)col[j] * 32 + q];
    a0 += bf4_to_f32(uint2{v.x, v.y}); a1 += bf4_to_f32(uint2{v.z, v.w});
  }
  #pragma unroll
  for (int c = 0; c < 4; ++c) {                     // combine halves
    a0[c] += __shfl_xor(a0[c], 32);
    a1[c] += __shfl_xor(a1[c], 32);
  }
  if (half == 0) {
    const float dn = dinv[n];
    f32x4 b0 = *(const f32x4*)(bias + q * 8);
    f32x4 b1 = *(const f32x4*)(bias + q * 8 + 4);
    float r0 = fmaxf(a0[0]*dn + b0[0], 0.f), r1 = fmaxf(a0[1]*dn + b0[1], 0.f);
    float r2 = fmaxf(a0[2]*dn + b0[2], 0.f), r3 = fmaxf(a0[3]*dn + b0[3], 0.f);
    float r4 = fmaxf(a1[0]*dn + b1[0], 0.f), r5 = fmaxf(a1[1]*dn + b1[1], 0.f);
    float r6 = fmaxf(a1[2]*dn + b1[2], 0.f), r7 = fmaxf(a1[3]*dn + b1[3], 0.f);
    uint4 o;
    o.x = cvtpk(r0, r1); o.y = cvtpk(r2, r3); o.z = cvtpk(r4, r5); o.w = cvtpk(r6, r7);
    ((uint4*)h2)[(size_t)n * 32 + q] = o;
  }
}

// ---- fused mean-pool (batch sorted -> binary search) + 2-layer MLP
__global__ __launch_bounds__(1024) void k_pool(const unsigned short* __restrict__ h2,
                                               const int* __restrict__ batch,
                                               const float* __restrict__ W1,
                                               const float* __restrict__ b1,
                                               const float* __restrict__ W2,
                                               const float* __restrict__ b2,
                                               float* __restrict__ out) {
  __shared__ f32x4 gp[16][64];
  __shared__ float gs[256];
  __shared__ float a1s[16];
  const int gi = blockIdx.x;
  const int tid = threadIdx.x;
  const int c4 = tid & 63, q = tid >> 6;            // 16 row-groups x 64 col-chunks(4)
  int lo = 0, hi = NN;
  while (lo < hi) { int mid = (lo + hi) >> 1; if (batch[mid] < gi) lo = mid + 1; else hi = mid; }
  const int s_ = lo;
  hi = NN;
  while (lo < hi) { int mid = (lo + hi) >> 1; if (batch[mid] < gi + 1) lo = mid + 1; else hi = mid; }
  const int e_ = lo;
  f32x4 sum = {0.f,0.f,0.f,0.f};
  for (int n = s_ + q; n < e_; n += 16)
    sum += bf4_to_f32(*(const uint2*)(h2 + (size_t)n * HID + c4 * 4));
  gp[q][c4] = sum;
  __syncthreads();
  if (tid < 64) {
    f32x4 tot = gp[0][tid];
    #pragma unroll
    for (int g = 1; g < 16; ++g) tot += gp[g][tid];
    const float inv = 1.0f / fmaxf((float)(e_ - s_), 1.0f);
    gs[tid*4+0] = tot[0]*inv; gs[tid*4+1] = tot[1]*inv;
    gs[tid*4+2] = tot[2]*inv; gs[tid*4+3] = tot[3]*inv;
  }
  __syncthreads();
  if (tid < 16) {
    float acc = b1[tid];
    #pragma unroll 4
    for (int k = 0; k < 256; ++k) acc += gs[k] * W1[k * 16 + tid];
    a1s[tid] = fmaxf(acc, 0.0f);
  }
  __syncthreads();
  if (tid < 10) {
    float acc = b2[tid];
    #pragma unroll
    for (int k = 0; k < 16; ++k) acc += a1s[k] * W2[k * 10 + tid];
    out[gi * 10 + tid] = acc;
  }
}

extern "C" void kernel_launch(void* const* d_in, const int* in_sizes, int n_in,
                              void* d_out, int out_size, void* d_ws, size_t ws_size,
                              hipStream_t stream) {
  const float* x     = (const float*)d_in[0];
  const int*   ei    = (const int*)d_in[1];      // [2,E]: src then dst
  const int*   batch = (const int*)d_in[2];
  const float* W     = (const float*)d_in[3];
  const float* b     = (const float*)d_in[4];
  const float* W1    = (const float*)d_in[5];
  const float* b1    = (const float*)d_in[6];
  const float* W2    = (const float*)d_in[7];
  const float* b2    = (const float*)d_in[8];
  float* out = (float*)d_out;
  char* ws = (char*)d_ws;

  size_t o = 0;
  auto al = [&](size_t bytes) { size_t r = o; o = (o + bytes + 255) & ~(size_t)255; return r; };
  unsigned short* wt = (unsigned short*)(ws + al((size_t)KIN * HID * 2));
  float* dinv        = (float*)(ws + al((size_t)NN * 4));
  int*   cnt         = (int*)(ws + al((size_t)NN * 4));
  int*   fill        = (int*)(ws + al((size_t)NN * 4));
  int*   rowptr      = (int*)(ws + al((size_t)(NN + 1) * 4));
  int*   col         = (int*)(ws + al((size_t)NE * 4));
  int*   bsum        = (int*)(ws + al((size_t)256 * 4));
  int*   boff        = (int*)(ws + al((size_t)256 * 4));
  unsigned short* hs = (unsigned short*)(ws + al((size_t)NN * HID * 2));
  unsigned short* h2 = (unsigned short*)(ws + al((size_t)NN * HID * 2));

  const int* src = ei;
  const int* dst = ei + NE;

  // zero cnt + fill (adjacent region)
  hipMemsetAsync(cnt, 0, (size_t)((char*)fill - (char*)cnt) + (size_t)NN * 4, stream);

  k_wt     <<<(KIN * HID) / 256, 256, 0, stream>>>(W, wt);
  k_deg    <<<(NE + 255) / 256, 256, 0, stream>>>(dst, cnt);
  k_dinv   <<<(NN + 255) / 256, 256, 0, stream>>>(cnt, dinv);
  k_scan1  <<<NB, 256, 0, stream>>>(cnt, bsum);
  k_scan2  <<<1, 256, 0, stream>>>(bsum, boff, rowptr);
  k_scan3  <<<NB, 256, 0, stream>>>(cnt, boff, rowptr);
  k_scatter<<<(NE + 255) / 256, 256, 0, stream>>>(dst, src, rowptr, fill, col);
  k_gemm   <<<((NN + 127) / 128) * 2, 256, 0, stream>>>(x, wt, dinv, hs);
  k_agg    <<<NN / 4, 256, 0, stream>>>(hs, rowptr, col, dinv, b, h2);
  k_pool   <<<NG, 1024, 0, stream>>>(h2, batch, W1, b1, W2, b2, out);
}